// Round 6
// baseline (44.059 us; speedup 1.0000x reference)
//
#include <hip/hip_runtime.h>
#include <math.h>

#define TPB 512           // 8 waves/block
#define CH  16            // samples per chunk
#define CPB 8             // chunks per block

static constexpr int B_     = 64;
static constexpr int S_     = 2048;
static constexpr int TOTAL  = B_ * S_;          // 131072 samples
static constexpr int NCHUNK = TOTAL / CH;       // 8192
static constexpr int NBLK   = NCHUNK / CPB;     // 1024 blocks = 4/CU exactly
static constexpr int SAMPB  = 600;              // bytes per sample (150 f32)
static constexpr int PREDB  = (CH + 2) * SAMPB; // 10800 B pred incl. 2-sample halo
static constexpr int TGTB   = CH * SAMPB;       // 9600 B tgt
static constexpr int CHB    = PREDB + TGTB;     // 20400 B staged per chunk
static constexpr int BUFB   = 20480;            // 20 slices x 1024 B (80 B slack)
static constexpr long TOTB  = (long)TOTAL * SAMPB;

// ---- union bone table: 51 edges covers bone-set(49) + conn-set(49) ----
// k=9,10 conn-only -> sentinel ranges; k=7,8 bone-only -> wsup=0.
// k>=11 (hand edges): min=0.01, max=0.08, wsup=1 computed in code.
__constant__ int US_[51] = {0,1,1,2,3,5,6,4,7,7,4,
    8,8,8,8,8,9,10,11,13,14,
    15,17,18,19,21,22,23,25,26,27,
    29,29,29,29,29,30,31,32,34,35,
    36,38,39,40,42,43,44,46,47,48};
__constant__ int UE_[51] = {1,2,5,3,4,6,7,8,29,8,29,
    9,13,17,21,25,10,11,12,14,15,
    16,18,19,20,22,23,24,26,27,28,
    30,34,38,42,46,31,32,33,35,36,
    37,39,40,41,43,44,45,47,48,49};
__constant__ float UMIN11_[11] = {0.05f,0.1f,0.1f,0.2f,0.2f,0.2f,0.2f,0.05f,0.05f,-1e9f,-1e9f};
__constant__ float UMAX11_[11] = {0.15f,0.2f,0.2f,0.35f,0.35f,0.35f,0.35f,0.15f,0.15f,1e9f,1e9f};
__constant__ float WSUP11_[11] = {1.f,1.f,1.f,1.f,1.f,1.f,1.f,0.f,0.f,1.f,1.f};
__constant__ int SL_[24] = {8,9,10,11,12,13,14,15,16,17,18,19,20,21,22,23,24,25,26,27,28,2,3,4};
__constant__ int SR_[24] = {29,30,31,32,33,34,35,36,37,38,39,40,41,42,43,44,45,46,47,48,49,5,6,7};
__constant__ int AJ_[4] = {1,1,2,5};
__constant__ int BJ_[4] = {2,5,3,6};
__constant__ int CJ_[4] = {3,6,4,7};

struct F3 { float x, y, z; };
__device__ __forceinline__ F3 ld3(const float* p) { return *(const F3*)p; }

typedef const __attribute__((address_space(1))) void* gas_t;
typedef __attribute__((address_space(3))) void* las_t;

__global__ __launch_bounds__(TPB, 8) void pose_main(
    const float* __restrict__ pred, const float* __restrict__ tgt,
    float* __restrict__ part)
{
    __shared__ __align__(16) char LDS[2 * BUFB];   // 40960 B; 4 blocks = 160 KiB exactly

    const int tid = threadIdx.x;
    const int blk = blockIdx.x;
    const int li  = tid & 15;
    const int g   = tid >> 4;        // 0..31
    const int jb  = li * 150;

    // ================= hoisted per-thread constants =================
    // union slot0: k = g (0..31, all threads)
    const int   uS0 = jb + US_[g] * 3, uE0 = jb + UE_[g] * 3;
    const float uMn0 = (g < 11) ? UMIN11_[g] : 0.01f;
    const float uMx0 = (g < 11) ? UMAX11_[g] : 0.08f;
    const float uW0  = (g < 11) ? WSUP11_[g] : 1.f;
    // union slot1: k = g+32 (32..50) for g<19 — all hand edges (k>=11)
    const bool u1_on = (g < 19);
    const int  k1u   = u1_on ? g + 32 : 50;       // clamp: no OOB table read
    const int  uS1 = jb + US_[k1u] * 3, uE1 = jb + UE_[k1u] * 3;
    // symmetry: k = g for g<24 (waves 0-5, wave-uniform)
    const bool sy_on = (g < 24);
    const int  ks  = sy_on ? g : 0;
    const int  s0L = jb + SL_[ks] * 3, s0R = jb + SR_[ks] * 3;
    // angle: k = g for g<4 (wave 0)
    const int aA = jb + AJ_[g & 3] * 3, aB = jb + BJ_[g & 3] * 3, aC = jb + CJ_[g & 3] * 3;
    // temporal: slot0 j=g (all); slot1 j=g+32 for g<18 (addr = tb0 + 96)
    const int  tb0 = jb + 3 * g;
    const bool t1_on = (g < 18);

    float a_bone = 0.f, a_ang = 0.f, a_sym = 0.f, a_vel = 0.f, a_acc = 0.f, a_sup = 0.f;

    // ============ async HBM->LDS staging: 20 wave-slices of 1024 B ============
    // wave w stages slices {w, w+8, w+16<20}; LDS dest wave-uniform, HW adds lane*16.
    const int w      = tid >> 6;
    const int lane16 = (tid & 63) << 4;
    auto stage = [&](int cidx, char* lbuf) {
        const long nb = (long)cidx * TGTB;
        const char* pb = (const char*)pred + nb;
        const char* tb = (const char*)tgt  + nb - PREDB;
        const long prem = TOTB - nb - 16;        // clamp pred halo at buffer end
        #pragma unroll
        for (int s = 0; s < 3; ++s) {
            const int slice = w + s * 8;
            if (slice < 20) {                    // wave-uniform
                const long o = (long)slice * 1024 + lane16;
                const char* src = (o < PREDB)
                    ? pb + (o > prem ? prem : o)
                    : tb + (o > (long)(CHB - 16) ? (long)(CHB - 16) : o);
                __builtin_amdgcn_global_load_lds((gas_t)src, (las_t)(lbuf + slice * 1024), 16, 0, 0);
            }
        }
    };

    const int c0 = blk * CPB;
    stage(c0, LDS);                  // prologue: chunk 0 -> buf0

    #pragma unroll
    for (int c = 0; c < CPB; ++c) {
        char* curb = LDS + (c & 1) * BUFB;
        char* nxtb = LDS + ((c & 1) ^ 1) * BUFB;
        if (c + 1 < CPB) {
            stage(c0 + c + 1, nxtb);             // prefetch next chunk
            // counted wait: current chunk's loads landed (3 for waves 0-3, 2 for 4-7)
            if (tid < 256) asm volatile("s_waitcnt vmcnt(3)" ::: "memory");
            else           asm volatile("s_waitcnt vmcnt(2)" ::: "memory");
        } else {
            asm volatile("s_waitcnt vmcnt(0)" ::: "memory");
        }
        __builtin_amdgcn_s_barrier();            // everyone's cur loads landed
        __builtin_amdgcn_sched_barrier(0);       // no ds_read hoisted above this

        const float* Jl = (const float*)curb;
        const float* Tl = Jl + PREDB / 4;
        const int cidx = c0 + c;

        // ---------- union: bone penalty + supervised ----------
        {
            const F3 je = ld3(Jl + uE0), js = ld3(Jl + uS0);
            const float dx = je.x - js.x, dy = je.y - js.y, dz = je.z - js.z;
            const float pb = sqrtf(dx * dx + dy * dy + dz * dz);
            a_bone += fmaxf(pb - uMx0, 0.f) + fmaxf(uMn0 - pb, 0.f);
            const F3 te = ld3(Tl + uE0), ts = ld3(Tl + uS0);
            const float tx = te.x - ts.x, ty = te.y - ts.y, tz = te.z - ts.z;
            const float tb = sqrtf(tx * tx + ty * ty + tz * tz);
            a_sup += uW0 * fabsf(pb - tb);
        }
        if (u1_on) {   // hand edges k=32..50: min=0.01 max=0.08 wsup=1
            const F3 je = ld3(Jl + uE1), js = ld3(Jl + uS1);
            const float dx = je.x - js.x, dy = je.y - js.y, dz = je.z - js.z;
            const float pb = sqrtf(dx * dx + dy * dy + dz * dz);
            a_bone += fmaxf(pb - 0.08f, 0.f) + fmaxf(0.01f - pb, 0.f);
            const F3 te = ld3(Tl + uE1), ts = ld3(Tl + uS1);
            const float tx = te.x - ts.x, ty = te.y - ts.y, tz = te.z - ts.z;
            const float tb = sqrtf(tx * tx + ty * ty + tz * tz);
            a_sup += fabsf(pb - tb);
        }

        // ---------- symmetry (waves 0-5) ----------
        if (sy_on) {
            const F3 L = ld3(Jl + s0L), R = ld3(Jl + s0R);
            a_sym += fabsf(L.x + R.x) + 0.5f * (fabsf(L.y - R.y) + fabsf(L.z - R.z));
        }

        // ---------- angles (wave 0 only) ----------
        if (tid < 64) {
            const F3 A = ld3(Jl + aA), Bb = ld3(Jl + aB), C = ld3(Jl + aC);
            const float v1x = A.x - Bb.x, v1y = A.y - Bb.y, v1z = A.z - Bb.z;
            const float v2x = C.x - Bb.x, v2y = C.y - Bb.y, v2z = C.z - Bb.z;
            const float n12 = (v1x*v1x + v1y*v1y + v1z*v1z) * (v2x*v2x + v2y*v2y + v2z*v2z);
            const float inv = __frsqrt_rn(fmaxf(n12, 1e-24f));
            float cosv = (v1x*v2x + v1y*v2y + v1z*v2z) * inv;
            cosv = fminf(fmaxf(cosv, -1.f), 1.f);
            const float deg = acosf(cosv) * 57.29577951308232f;
            a_ang += fmaxf(30.f - deg, 0.f) + fmaxf(deg - 150.f, 0.f);
        }

        // ---------- temporal ----------
        {
            const int sidx = ((cidx * CH) & (S_ - 1)) + li;
            const bool v_ok = sidx < S_ - 1;
            const bool a_ok = sidx < S_ - 2;
            {
                const float* tp = Jl + tb0;              // j = g
                const F3 p0 = ld3(tp), p1 = ld3(tp + 150), p2 = ld3(tp + 300);
                if (v_ok) {
                    const float vx = p1.x - p0.x, vy = p1.y - p0.y, vz = p1.z - p0.z;
                    a_vel += sqrtf(vx*vx + vy*vy + vz*vz);
                    if (a_ok) {
                        const float ax = p2.x - 2.f*p1.x + p0.x;
                        const float ay = p2.y - 2.f*p1.y + p0.y;
                        const float az = p2.z - 2.f*p1.z + p0.z;
                        a_acc += sqrtf(ax*ax + ay*ay + az*az);
                    }
                }
            }
            if (t1_on) {                                  // j = g+32
                const float* tq = Jl + tb0 + 96;
                const F3 p0 = ld3(tq), p1 = ld3(tq + 150), p2 = ld3(tq + 300);
                if (v_ok) {
                    const float vx = p1.x - p0.x, vy = p1.y - p0.y, vz = p1.z - p0.z;
                    a_vel += sqrtf(vx*vx + vy*vy + vz*vz);
                    if (a_ok) {
                        const float ax = p2.x - 2.f*p1.x + p0.x;
                        const float ay = p2.y - 2.f*p1.y + p0.y;
                        const float az = p2.z - 2.f*p1.z + p0.z;
                        a_acc += sqrtf(ax*ax + ay*ay + az*az);
                    }
                }
            }
        }

        asm volatile("" ::: "memory");   // block LDS-load CSE across chunk iterations
        __builtin_amdgcn_s_barrier();    // all done reading curb before it is restaged
    }

    // ================= block reduction =================
    float vals[6] = {a_bone, a_ang, a_sym, a_vel, a_acc, a_sup};
    #pragma unroll
    for (int k = 0; k < 6; ++k)
        #pragma unroll
        for (int off = 32; off > 0; off >>= 1)
            vals[k] += __shfl_down(vals[k], off, 64);

    float* red = (float*)LDS;            // reuse staging LDS (final barrier passed)
    const int lane = tid & 63;
    if (lane == 0) {
        #pragma unroll
        for (int k = 0; k < 6; ++k) red[w * 6 + k] = vals[k];
    }
    __syncthreads();
    if (tid == 0) {
        #pragma unroll
        for (int k = 0; k < 6; ++k) {    // SoA partials: part[k][blk]
            float s = 0.f;
            #pragma unroll
            for (int v = 0; v < 8; ++v) s += red[v * 6 + k];
            part[k * NBLK + blk] = s;
        }
    }
}

__global__ __launch_bounds__(256) void pose_reduce(
    const float* __restrict__ part, float* __restrict__ out)
{
    __shared__ float red[4][6];
    const int tid = threadIdx.x;
    float a[6];
    #pragma unroll
    for (int k = 0; k < 6; ++k) {
        float s = 0.f;
        for (int i = tid; i < NBLK; i += 256) s += part[k * NBLK + i];
        a[k] = s;
    }
    #pragma unroll
    for (int k = 0; k < 6; ++k)
        #pragma unroll
        for (int off = 32; off > 0; off >>= 1)
            a[k] += __shfl_down(a[k], off, 64);

    const int wid = tid >> 6, lane = tid & 63;
    if (lane == 0) {
        #pragma unroll
        for (int k = 0; k < 6; ++k) red[wid][k] = a[k];
    }
    __syncthreads();
    if (tid == 0) {
        float t[6];
        #pragma unroll
        for (int k = 0; k < 6; ++k) t[k] = red[0][k] + red[1][k] + red[2][k] + red[3][k];
        const float bone = t[0] * (1.f / ((float)TOTAL * 49.f));
        const float ang  = t[1] * (1.f / ((float)TOTAL * 4.f));
        const float sym  = t[2] * (1.f / ((float)TOTAL * 24.f));
        const float temporal = t[4] * (1.f / ((float)B_ * (float)(S_ - 2) * 50.f))
                             + 0.5f * t[3] * (1.f / ((float)B_ * (float)(S_ - 1) * 50.f));
        const float sup  = t[5] * (1.f / ((float)TOTAL * 49.f));
        out[0] = bone;
        out[1] = ang;
        out[2] = sym;
        out[3] = temporal;
        out[4] = sup;
        out[5] = bone + 0.5f * ang + 0.3f * sym + 0.2f * temporal + sup;
    }
}

extern "C" void kernel_launch(void* const* d_in, const int* in_sizes, int n_in,
                              void* d_out, int out_size, void* d_ws, size_t ws_size,
                              hipStream_t stream)
{
    const float* pred = (const float*)d_in[0];
    const float* tgt  = (const float*)d_in[1];
    float* part = (float*)d_ws;   // 6 * 1024 f32 = 24 KB (SoA)
    pose_main<<<NBLK, TPB, 0, stream>>>(pred, tgt, part);
    pose_reduce<<<1, 256, 0, stream>>>(part, (float*)d_out);
}

// Round 7
// 39.265 us; speedup vs baseline: 1.1221x; 1.1221x over previous
//
#include <hip/hip_runtime.h>
#include <math.h>

#define TPB 512           // 8 waves/block
#define CH  32            // samples per chunk
#define CPB 8             // chunks per block

static constexpr int B_     = 64;
static constexpr int S_     = 2048;
static constexpr int TOTAL  = B_ * S_;          // 131072 samples
static constexpr int NCHUNK = TOTAL / CH;       // 4096
static constexpr int NBLK   = NCHUNK / CPB;     // 512 blocks = 2/CU exactly
static constexpr int SAMPB  = 600;              // bytes per sample (150 f32)
static constexpr int PREDB  = (CH + 2) * SAMPB; // 20400 B pred incl. 2-sample halo
static constexpr int TGTB   = CH * SAMPB;       // 19200 B tgt
static constexpr int CHB    = PREDB + TGTB;     // 39600 B staged per chunk
static constexpr int NSLICE = 39;               // ceil(CHB/1024)
static constexpr int BUFB   = NSLICE * 1024;    // 39936; 2 bufs = 79872 B (<160KiB/2)
static constexpr long TOTB  = (long)TOTAL * SAMPB;

// ---- union bone table: 51 edges covers bone-set(49) + conn-set(49) ----
// k=9,10 conn-only -> sentinel ranges; k=7,8 bone-only -> wsup=0.
// k>=11 (hand edges): min=0.01, max=0.08, wsup=1 (compile-time constants).
__constant__ int US_[51] = {0,1,1,2,3,5,6,4,7,7,4,
    8,8,8,8,8,9,10,11,13,14,
    15,17,18,19,21,22,23,25,26,27,
    29,29,29,29,29,30,31,32,34,35,
    36,38,39,40,42,43,44,46,47,48};
__constant__ int UE_[51] = {1,2,5,3,4,6,7,8,29,8,29,
    9,13,17,21,25,10,11,12,14,15,
    16,18,19,20,22,23,24,26,27,28,
    30,34,38,42,46,31,32,33,35,36,
    37,39,40,41,43,44,45,47,48,49};
__constant__ float UMIN11_[11] = {0.05f,0.1f,0.1f,0.2f,0.2f,0.2f,0.2f,0.05f,0.05f,-1e9f,-1e9f};
__constant__ float UMAX11_[11] = {0.15f,0.2f,0.2f,0.35f,0.35f,0.35f,0.35f,0.15f,0.15f,1e9f,1e9f};
__constant__ float WSUP11_[11] = {1.f,1.f,1.f,1.f,1.f,1.f,1.f,0.f,0.f,1.f,1.f};
__constant__ int SL_[24] = {8,9,10,11,12,13,14,15,16,17,18,19,20,21,22,23,24,25,26,27,28,2,3,4};
__constant__ int SR_[24] = {29,30,31,32,33,34,35,36,37,38,39,40,41,42,43,44,45,46,47,48,49,5,6,7};
__constant__ int AJ_[4] = {1,1,2,5};
__constant__ int BJ_[4] = {2,5,3,6};
__constant__ int CJ_[4] = {3,6,4,7};

struct F3 { float x, y, z; };
__device__ __forceinline__ F3 ld3(const float* p) { return *(const F3*)p; }
#define SQRTF __builtin_amdgcn_sqrtf

typedef const __attribute__((address_space(1))) void* gas_t;
typedef __attribute__((address_space(3))) void* las_t;

__global__ __launch_bounds__(TPB, 4) void pose_main(
    const float* __restrict__ pred, const float* __restrict__ tgt,
    float* __restrict__ part)
{
    __shared__ __align__(16) char LDS[2 * BUFB];   // 79872 B -> 2 blocks/CU

    const int tid = threadIdx.x;
    const int blk = blockIdx.x;
    const int li  = tid & 31;        // sample within chunk (0..31)
    const int g   = tid >> 5;        // group 0..15
    const int jb  = li * 150;

    // ================= hoisted per-thread constants =================
    // union slots: k = g, g+16, g+32; extra k=48+g for g<3.
    const int   uS0 = jb + US_[g] * 3,      uE0 = jb + UE_[g] * 3;
    const float uMn0 = (g < 11) ? UMIN11_[g] : 0.01f;
    const float uMx0 = (g < 11) ? UMAX11_[g] : 0.08f;
    const float uW0  = (g < 11) ? WSUP11_[g] : 1.f;
    const int   uS1 = jb + US_[g + 16] * 3, uE1 = jb + UE_[g + 16] * 3;
    const int   uS2 = jb + US_[g + 32] * 3, uE2 = jb + UE_[g + 32] * 3;
    const int   kx  = 48 + (g < 3 ? g : 0);
    const int   uSx = jb + US_[kx] * 3,     uEx = jb + UE_[kx] * 3;
    // symmetry: k=g all; extra k=16+g for g<8
    const int s0L = jb + SL_[g] * 3,           s0R = jb + SR_[g] * 3;
    const int s1L = jb + SL_[16 + (g & 7)] * 3, s1R = jb + SR_[16 + (g & 7)] * 3;
    // angle: k=g for g<4
    const int aA = jb + AJ_[g & 3] * 3, aB = jb + BJ_[g & 3] * 3, aC = jb + CJ_[g & 3] * 3;
    // temporal: j = g, g+16, g+32; extra j=48,49 on g=4,5
    const int tb0 = jb + 3 * g;
    const int tbx = jb + 144 + ((g - 4) & 1) * 3;   // g=4 -> j48, g=5 -> j49
    const bool tex_on = (g == 4 || g == 5);

    float a_bone = 0.f, a_ang = 0.f, a_sym = 0.f, a_vel = 0.f, a_acc = 0.f, a_sup = 0.f;

    // ============ async HBM->LDS staging: 39 wave-slices of 1024 B ============
    // wave w stages slices {w+8s | s<5, w+8s<39}; waves 0-6: 5 loads, wave 7: 4.
    const int w      = tid >> 6;
    const int lane16 = (tid & 63) << 4;
    auto stage = [&](int cidx, char* lbuf) {
        const long nb = (long)cidx * TGTB;
        const char* pb = (const char*)pred + nb;
        const char* tb = (const char*)tgt  + nb - PREDB;
        const long prem = TOTB - nb - 16;        // clamp pred halo at buffer end
        #pragma unroll
        for (int s = 0; s < 5; ++s) {
            const int slice = w + s * 8;
            if (slice < NSLICE) {                // wave-uniform
                const long o = (long)slice * 1024 + lane16;
                const char* src = (o < PREDB)
                    ? pb + (o > prem ? prem : o)
                    : tb + (o > (long)(CHB - 16) ? (long)(CHB - 16) : o);
                __builtin_amdgcn_global_load_lds((gas_t)src, (las_t)(lbuf + slice * 1024), 16, 0, 0);
            }
        }
    };

    const int c0 = blk * CPB;
    stage(c0, LDS);                  // prologue: chunk 0 -> buf0

    #pragma unroll
    for (int c = 0; c < CPB; ++c) {
        char* curb = LDS + (c & 1) * BUFB;
        char* nxtb = LDS + ((c & 1) ^ 1) * BUFB;
        if (c + 1 < CPB) {
            stage(c0 + c + 1, nxtb);             // prefetch next chunk
            // counted wait: current chunk's loads landed (5/wave, 4 on wave 7)
            if (w < 7) asm volatile("s_waitcnt vmcnt(5)" ::: "memory");
            else       asm volatile("s_waitcnt vmcnt(4)" ::: "memory");
        } else {
            asm volatile("s_waitcnt vmcnt(0)" ::: "memory");
        }
        __builtin_amdgcn_s_barrier();            // everyone's cur loads landed
        __builtin_amdgcn_sched_barrier(0);       // no ds_read hoisted above this

        const float* Jl = (const float*)curb;
        const float* Tl = Jl + PREDB / 4;
        const int cidx = c0 + c;

        // ---------- union: bone penalty + supervised ----------
        auto edge = [&](int so, int eo, float mn, float mx, float wsup) {
            const F3 je = ld3(Jl + eo), js = ld3(Jl + so);
            const float dx = je.x - js.x, dy = je.y - js.y, dz = je.z - js.z;
            const float pb = SQRTF(dx * dx + dy * dy + dz * dz);
            a_bone += fmaxf(pb - mx, 0.f) + fmaxf(mn - pb, 0.f);
            const F3 te = ld3(Tl + eo), ts = ld3(Tl + so);
            const float tx = te.x - ts.x, ty = te.y - ts.y, tz = te.z - ts.z;
            const float tb = SQRTF(tx * tx + ty * ty + tz * tz);
            a_sup += wsup * fabsf(pb - tb);
        };
        edge(uS0, uE0, uMn0, uMx0, uW0);
        edge(uS1, uE1, 0.01f, 0.08f, 1.f);
        edge(uS2, uE2, 0.01f, 0.08f, 1.f);
        if (g < 3) edge(uSx, uEx, 0.01f, 0.08f, 1.f);

        // ---------- symmetry ----------
        auto sym = [&](int l3, int r3) {
            const F3 L = ld3(Jl + l3), R = ld3(Jl + r3);
            a_sym += fabsf(L.x + R.x) + 0.5f * (fabsf(L.y - R.y) + fabsf(L.z - R.z));
        };
        sym(s0L, s0R);
        if (g < 8) sym(s1L, s1R);

        // ---------- angles (g<4) ----------
        if (g < 4) {
            const F3 A = ld3(Jl + aA), Bb = ld3(Jl + aB), C = ld3(Jl + aC);
            const float v1x = A.x - Bb.x, v1y = A.y - Bb.y, v1z = A.z - Bb.z;
            const float v2x = C.x - Bb.x, v2y = C.y - Bb.y, v2z = C.z - Bb.z;
            const float n12 = (v1x*v1x + v1y*v1y + v1z*v1z) * (v2x*v2x + v2y*v2y + v2z*v2z);
            const float inv = __frsqrt_rn(fmaxf(n12, 1e-24f));
            float cosv = (v1x*v2x + v1y*v2y + v1z*v2z) * inv;
            cosv = fminf(fmaxf(cosv, -1.f), 1.f);
            const float deg = acosf(cosv) * 57.29577951308232f;
            a_ang += fmaxf(30.f - deg, 0.f) + fmaxf(deg - 150.f, 0.f);
        }

        // ---------- temporal ----------
        {
            const int sidx = ((cidx * CH) & (S_ - 1)) + li;
            const bool v_ok = sidx < S_ - 1;
            const bool a_ok = sidx < S_ - 2;
            auto temporal = [&](int base) {
                const F3 p0 = ld3(Jl + base), p1 = ld3(Jl + base + 150), p2 = ld3(Jl + base + 300);
                if (v_ok) {
                    const float vx = p1.x - p0.x, vy = p1.y - p0.y, vz = p1.z - p0.z;
                    a_vel += SQRTF(vx*vx + vy*vy + vz*vz);
                    if (a_ok) {
                        const float ax = p2.x - 2.f*p1.x + p0.x;
                        const float ay = p2.y - 2.f*p1.y + p0.y;
                        const float az = p2.z - 2.f*p1.z + p0.z;
                        a_acc += SQRTF(ax*ax + ay*ay + az*az);
                    }
                }
            };
            temporal(tb0);        // j = g
            temporal(tb0 + 48);   // j = g+16
            temporal(tb0 + 96);   // j = g+32
            if (tex_on) temporal(tbx);   // j = 48,49
        }

        asm volatile("" ::: "memory");   // block LDS-load CSE across chunk iterations
        __builtin_amdgcn_s_barrier();    // all done reading curb before it is restaged
    }

    // ================= block reduction =================
    float vals[6] = {a_bone, a_ang, a_sym, a_vel, a_acc, a_sup};
    #pragma unroll
    for (int k = 0; k < 6; ++k)
        #pragma unroll
        for (int off = 32; off > 0; off >>= 1)
            vals[k] += __shfl_down(vals[k], off, 64);

    float* red = (float*)LDS;            // reuse staging LDS (final barrier passed)
    const int lane = tid & 63;
    if (lane == 0) {
        #pragma unroll
        for (int k = 0; k < 6; ++k) red[w * 6 + k] = vals[k];
    }
    __syncthreads();
    if (tid == 0) {
        #pragma unroll
        for (int k = 0; k < 6; ++k) {    // SoA partials: part[k][blk]
            float s = 0.f;
            #pragma unroll
            for (int v = 0; v < 8; ++v) s += red[v * 6 + k];
            part[k * NBLK + blk] = s;
        }
    }
}

__global__ __launch_bounds__(256) void pose_reduce(
    const float* __restrict__ part, float* __restrict__ out)
{
    __shared__ float red[4][6];
    const int tid = threadIdx.x;
    float a[6];
    #pragma unroll
    for (int k = 0; k < 6; ++k) {
        float s = 0.f;
        for (int i = tid; i < NBLK; i += 256) s += part[k * NBLK + i];
        a[k] = s;
    }
    #pragma unroll
    for (int k = 0; k < 6; ++k)
        #pragma unroll
        for (int off = 32; off > 0; off >>= 1)
            a[k] += __shfl_down(a[k], off, 64);

    const int wid = tid >> 6, lane = tid & 63;
    if (lane == 0) {
        #pragma unroll
        for (int k = 0; k < 6; ++k) red[wid][k] = a[k];
    }
    __syncthreads();
    if (tid == 0) {
        float t[6];
        #pragma unroll
        for (int k = 0; k < 6; ++k) t[k] = red[0][k] + red[1][k] + red[2][k] + red[3][k];
        const float bone = t[0] * (1.f / ((float)TOTAL * 49.f));
        const float ang  = t[1] * (1.f / ((float)TOTAL * 4.f));
        const float sym  = t[2] * (1.f / ((float)TOTAL * 24.f));
        const float temporal = t[4] * (1.f / ((float)B_ * (float)(S_ - 2) * 50.f))
                             + 0.5f * t[3] * (1.f / ((float)B_ * (float)(S_ - 1) * 50.f));
        const float sup  = t[5] * (1.f / ((float)TOTAL * 49.f));
        out[0] = bone;
        out[1] = ang;
        out[2] = sym;
        out[3] = temporal;
        out[4] = sup;
        out[5] = bone + 0.5f * ang + 0.3f * sym + 0.2f * temporal + sup;
    }
}

extern "C" void kernel_launch(void* const* d_in, const int* in_sizes, int n_in,
                              void* d_out, int out_size, void* d_ws, size_t ws_size,
                              hipStream_t stream)
{
    const float* pred = (const float*)d_in[0];
    const float* tgt  = (const float*)d_in[1];
    float* part = (float*)d_ws;   // 6 * 512 f32 = 12 KB (SoA)
    pose_main<<<NBLK, TPB, 0, stream>>>(pred, tgt, part);
    pose_reduce<<<1, 256, 0, stream>>>(part, (float*)d_out);
}